// Round 22
// baseline (108.979 us; speedup 1.0000x reference)
//
#include <hip/hip_runtime.h>

#define NN 1024
#define DG 8
#define FO 64
#define FI 128
#define LALPHA 0.2f
#define BR 8         // output rows per fused block (R22: 16 -> 8 for 2x occupancy)
#define SBS 257      // Sb row stride (u32 words)
#define RDS 68       // reduction row stride (floats)

typedef __attribute__((ext_vector_type(8))) short bf16x8;
typedef __attribute__((ext_vector_type(4))) float f32x4;

static __device__ __forceinline__ unsigned short f2bf(float x) {
  union { float f; unsigned u; } v; v.f = x;
  unsigned r = v.u + 0x7FFFu + ((v.u >> 16) & 1u);  // round-to-nearest-even
  return (unsigned short)(r >> 16);
}
static __device__ __forceinline__ float bf2f(unsigned short h) {
  union { unsigned u; float f; } v; v.u = ((unsigned)h) << 16;
  return v.f;
}

// ---------------------------------------------------------------------------
// K1 (prep): unchanged (measured 8.1 us, round 17).
// ---------------------------------------------------------------------------
__global__ __launch_bounds__(256) void k_prep(const float* __restrict__ atoms,
                                              const float* __restrict__ W,
                                              const float* __restrict__ a,
                                              const int* __restrict__ edges,
                                              int* __restrict__ uniq,
                                              ushort* __restrict__ hT,
                                              ushort* __restrict__ hN,
                                              float* __restrict__ srcv,
                                              float* __restrict__ dstv) {
  __shared__ float sp[16], dp[16];
  const int t = threadIdx.x, b = blockIdx.x;
  const int g = b >> 6;
  const int rbase = b * 16;

  if (t < 16) {
    sp[t] = 0.f; dp[t] = 0.f;
    const int rr = rbase + t;
    int e[DG];
#pragma unroll
    for (int s = 0; s < DG; s++) e[s] = edges[rr * DG + s];
#pragma unroll
    for (int s = 0; s < DG; s++) {
      int v = e[s];
      bool dup = false;
#pragma unroll
      for (int q = 0; q < DG; q++)
        if (q < s && e[q] == v) dup = true;
      uniq[rr * DG + s] = dup ? -1 : v;
    }
  }

  const int w = t >> 6, lane = t & 63, quad = lane >> 4, l16 = lane & 15;
  const float* __restrict__ Ar = atoms + (size_t)(rbase + l16) * FI;
  const float* __restrict__ Wc = W + w * 16 + l16;
  f32x4 acc = {0.f, 0.f, 0.f, 0.f};
#pragma unroll
  for (int kc = 0; kc < 4; kc++) {
    const int k0 = kc * 32 + quad * 8;
    float4 a0 = *(const float4*)(Ar + k0);
    float4 a1 = *(const float4*)(Ar + k0 + 4);
    float av[8] = {a0.x, a0.y, a0.z, a0.w, a1.x, a1.y, a1.z, a1.w};
    float wv[8];
#pragma unroll
    for (int e = 0; e < 8; e++) wv[e] = Wc[(k0 + e) * FO];
    bf16x8 ahi, alo, bhi, blo;
#pragma unroll
    for (int e = 0; e < 8; e++) {
      ushort h = f2bf(av[e]);
      ahi[e] = (short)h;
      alo[e] = (short)f2bf(av[e] - bf2f(h));
      ushort g2 = f2bf(wv[e]);
      bhi[e] = (short)g2;
      blo[e] = (short)f2bf(wv[e] - bf2f(g2));
    }
    acc = __builtin_amdgcn_mfma_f32_16x16x32_bf16(ahi, bhi, acc, 0, 0, 0);
    acc = __builtin_amdgcn_mfma_f32_16x16x32_bf16(ahi, blo, acc, 0, 0, 0);
    acc = __builtin_amdgcn_mfma_f32_16x16x32_bf16(alo, bhi, acc, 0, 0, 0);
  }

  const int f = w * 16 + l16;
  const float as_ = a[f], ad_ = a[FO + f];
  float ps[4], pd[4];
#pragma unroll
  for (int r = 0; r < 4; r++) {
    float v = acc[r];
    int rb = rbase + quad * 4 + r;
    ushort hv = f2bf(v);
    hT[((size_t)g * FO + f) * NN + (rb & (NN - 1))] = hv;
    hN[(size_t)rb * FO + f] = hv;
    ps[r] = v * as_;
    pd[r] = v * ad_;
  }
#pragma unroll
  for (int off = 1; off < 16; off <<= 1)
#pragma unroll
    for (int r = 0; r < 4; r++) {
      ps[r] += __shfl_xor(ps[r], off);
      pd[r] += __shfl_xor(pd[r], off);
    }
  __syncthreads();
  if (l16 == 0) {
#pragma unroll
    for (int r = 0; r < 4; r++) {
      atomicAdd(&sp[quad * 4 + r], ps[r]);
      atomicAdd(&dp[quad * 4 + r], pd[r]);
    }
  }
  __syncthreads();
  if (t < 16) {
    srcv[rbase + t] = sp[t];
    dstv[rbase + t] = dp[t];
  }
}

// ---------------------------------------------------------------------------
// K2 (fused): ROUND-22 CHANGE -- BR 16 -> 8. Grid doubles to 2048 blocks ->
// 8 blocks/CU x 4 waves = 32 waves/CU (100% occupancy, was 16/50%: the
// R20-probe showed MfmaUtil 5.8% / VALUBusy 24% / Occupancy 40% -- pure
// latency-bound at grid-capped TLP; R21 proved instruction placement is not
// a lever). LDS/block ~17.7 KB (8x = 142 KB < 160). __launch_bounds__(256,8)
// caps VGPR at 64 (probe VGPR was 56). GEMM A-rows clamp l16&7 (C rows 8-15
// are discarded duplicates; red write guarded quad<2; zred dup rows unused).
// R21 prefetch reverted (measured null). Arithmetic per output element
// identical -> absmax unchanged.
// ---------------------------------------------------------------------------
__global__ __launch_bounds__(256, 8) void k_fused(const int* __restrict__ uniq,
                                                  const float* __restrict__ srcv,
                                                  const float* __restrict__ dstv,
                                                  const ushort* __restrict__ hT,
                                                  const ushort* __restrict__ hN,
                                                  float* __restrict__ out) {
  __shared__ unsigned Sb[BR * SBS];                 // 8224 B byte counters
  __shared__ __align__(16) float red[4][BR][RDS];   // 8704 B k-split partials
  __shared__ float zred[4][16];
  __shared__ int n1[BR][DG];
  __shared__ float attw[BR][DG];

  const int t = threadIdx.x, b = blockIdx.x;
  const int g = b >> 7, rbase = (b & 127) * BR;
  const int* __restrict__ Ug = uniq + (size_t)g * NN * DG;

  for (int i = t; i < BR * SBS; i += 256) Sb[i] = 0u;
  if (t < BR * DG) n1[t >> 3][t & 7] = Ug[(rbase + (t >> 3)) * DG + (t & 7)];
  __syncthreads();

  // --- scatter: 512 items (r = idx&7, e = idx>>3), levels 1..3 fused ---
#pragma unroll
  for (int q = 0; q < 2; q++) {
    int idx = t + 256 * q;
    int r = idx & (BR - 1), e = idx >> 3;
    int j = n1[r][e >> 3];
    if (j >= 0) {
      if ((e & 7) == 0)  // level-1, once per (r,s)
        atomicAdd(&Sb[r * SBS + (j >> 2)], 1u << ((j & 3) * 8));
      int k = Ug[j * DG + (e & 7)];
      if (k >= 0) {
        atomicAdd(&Sb[r * SBS + (k >> 2)], 1u << ((k & 3) * 8));  // level-2
        int4 m0 = *(const int4*)(Ug + k * DG);
        int4 m1 = *(const int4*)(Ug + k * DG + 4);
        int ll[8] = {m0.x, m0.y, m0.z, m0.w, m1.x, m1.y, m1.z, m1.w};
#pragma unroll
        for (int e2 = 0; e2 < 8; e2++)  // level-3
          if (ll[e2] >= 0) atomicAdd(&Sb[r * SBS + (ll[e2] >> 2)], 1u << ((ll[e2] & 3) * 8));
      }
    }
  }
  // att softmax (t<8, one row each)
  if (t < BR) {
    int r = t;
    float si = srcv[g * NN + rbase + r];
    float ev[DG];
    float m = -1e30f;
#pragma unroll
    for (int s = 0; s < DG; s++) {
      int j = n1[r][s];
      if (j >= 0) {
        float x = si + dstv[g * NN + j];
        x = x > 0.f ? x : LALPHA * x;
        ev[s] = x;
        m = fmaxf(m, x);
      } else ev[s] = -1e30f;
    }
    float sm = 0.f;
#pragma unroll
    for (int s = 0; s < DG; s++) {
      float e = (n1[r][s] >= 0) ? __expf(ev[s] - m) : 0.f;
      ev[s] = e;
      sm += e;
    }
    float inv = 1.f / sm;
#pragma unroll
    for (int s = 0; s < DG; s++) attw[r][s] = ev[s] * inv;
  }
  __syncthreads();

  // --- attH in REGISTERS: t<128 -> (row rr_=t>>4 in 0..7, cols f0_..f0_+4) ---
  const int rr_ = t >> 4, f0_ = (t & 15) * 4;
  float ah0 = 0.f, ah1 = 0.f, ah2 = 0.f, ah3 = 0.f;
  if (t < BR * 16) {
#pragma unroll
    for (int s = 0; s < DG; s++) {
      int j = n1[rr_][s];
      if (j >= 0) {
        float wgt = attw[rr_][s];
        uint2 hv = *(const uint2*)(hN + ((size_t)(g * NN + j)) * FO + f0_);
        ah0 += wgt * bf2f((ushort)(hv.x & 0xffffu));
        ah1 += wgt * bf2f((ushort)(hv.x >> 16));
        ah2 += wgt * bf2f((ushort)(hv.y & 0xffffu));
        ah3 += wgt * bf2f((ushort)(hv.y >> 16));
      }
    }
  }

  // --- k-split GEMM: wave v covers nodes [v*256, v*256+256) ---
  const int v = t >> 6, lane = t & 63, quad = lane >> 4, l16 = lane & 15;
  const int r8 = l16 & (BR - 1);   // Sb row clamp: A rows 8-15 duplicate 0-7
  const int k0 = v * 256;
  const ushort* __restrict__ hb = hT + ((size_t)g * FO) * NN;
  f32x4 acc[4] = {{0.f, 0.f, 0.f, 0.f}, {0.f, 0.f, 0.f, 0.f},
                  {0.f, 0.f, 0.f, 0.f}, {0.f, 0.f, 0.f, 0.f}};
  float zacc = 0.f;
#pragma unroll
  for (int ks = 0; ks < 256; ks += 32) {
    const int wd = r8 * SBS + ((k0 + ks) >> 2) + quad * 2;
    unsigned s0 = Sb[wd], s1 = Sb[wd + 1];
    const int c0 = s0 & 255u, c1 = (s0 >> 8) & 255u, c2 = (s0 >> 16) & 255u, c3 = s0 >> 24;
    const int c4 = s1 & 255u, c5 = (s1 >> 8) & 255u, c6 = (s1 >> 16) & 255u, c7 = s1 >> 24;
    const float e0 = __expf((float)c0), e1 = __expf((float)c1);
    const float e2 = __expf((float)c2), e3 = __expf((float)c3);
    const float e4 = __expf((float)c4), e5 = __expf((float)c5);
    const float e6 = __expf((float)c6), e7 = __expf((float)c7);
    bf16x8 af;
    af[0] = (short)f2bf(e0); af[1] = (short)f2bf(e1);
    af[2] = (short)f2bf(e2); af[3] = (short)f2bf(e3);
    af[4] = (short)f2bf(e4); af[5] = (short)f2bf(e5);
    af[6] = (short)f2bf(e6); af[7] = (short)f2bf(e7);
    zacc += (e0 + e1) + (e2 + e3) + (e4 + e5) + (e6 + e7);
    const ushort* hp = hb + (size_t)l16 * NN + k0 + ks + quad * 8;
#pragma unroll
    for (int ct = 0; ct < 4; ct++) {
      bf16x8 bf = *(const bf16x8*)(hp + (size_t)(ct * 16) * NN);
      acc[ct] = __builtin_amdgcn_mfma_f32_16x16x32_bf16(af, bf, acc[ct], 0, 0, 0);
    }
  }
  zacc += __shfl_xor(zacc, 16);
  zacc += __shfl_xor(zacc, 32);
  if (lane < 16) zred[v][lane] = zacc;   // rows 8-15 are harmless duplicates
#pragma unroll
  for (int ct = 0; ct < 4; ct++)
#pragma unroll
    for (int r = 0; r < 4; r++)
      if (quad < 2)                      // C rows 0-7 only (8-15 = duplicates)
        red[v][quad * 4 + r][ct * 16 + l16] = acc[ct][r];
  __syncthreads();

  // --- epilogue: t<128 -> (row rr_ in 0..7, cols f0_..f0_+4), float4 ---
  if (t < BR * 16) {
    const float Z = zred[0][rr_] + zred[1][rr_] + zred[2][rr_] + zred[3][rr_];
    const float hz = 0.5f / Z;
    f32x4 s = *(const f32x4*)&red[0][rr_][f0_];
    f32x4 s1v = *(const f32x4*)&red[1][rr_][f0_];
    f32x4 s2v = *(const f32x4*)&red[2][rr_][f0_];
    f32x4 s3v = *(const f32x4*)&red[3][rr_][f0_];
    float o0 = 0.5f * ah0 + (s[0] + s1v[0] + s2v[0] + s3v[0]) * hz;
    float o1 = 0.5f * ah1 + (s[1] + s1v[1] + s2v[1] + s3v[1]) * hz;
    float o2 = 0.5f * ah2 + (s[2] + s1v[2] + s2v[2] + s3v[2]) * hz;
    float o3 = 0.5f * ah3 + (s[3] + s1v[3] + s2v[3] + s3v[3]) * hz;
    o0 = o0 > 0.f ? o0 : __expf(o0) - 1.f;
    o1 = o1 > 0.f ? o1 : __expf(o1) - 1.f;
    o2 = o2 > 0.f ? o2 : __expf(o2) - 1.f;
    o3 = o3 > 0.f ? o3 : __expf(o3) - 1.f;
    *(float4*)(out + ((size_t)(g * NN + rbase + rr_)) * FO + f0_) =
        make_float4(o0, o1, o2, o3);
  }
}

// ---------------------------------------------------------------------------
extern "C" void kernel_launch(void* const* d_in, const int* in_sizes, int n_in,
                              void* d_out, int out_size, void* d_ws, size_t ws_size,
                              hipStream_t stream) {
  const float* atoms = (const float*)d_in[0];
  const int* edges = (const int*)d_in[1];
  const float* W = (const float*)d_in[2];
  const float* a = (const float*)d_in[3];
  float* out = (float*)d_out;

  const int nrows = in_sizes[0] / FI;   // B*N = 16384
  const int ngraph = nrows / NN;        // 16

  ushort* hT = (ushort*)d_ws;                                   // ngraph*FO*NN
  ushort* hN = hT + (size_t)ngraph * FO * NN;                   // nrows*FO
  float* srcv = (float*)(hN + (size_t)nrows * FO);              // nrows
  float* dstv = srcv + nrows;                                   // nrows
  int* uniq = (int*)(dstv + nrows);                             // nrows*DG

  k_prep<<<nrows / 16, 256, 0, stream>>>(atoms, W, a, edges, uniq, hT, hN, srcv, dstv);
  k_fused<<<ngraph * (NN / BR), 256, 0, stream>>>(uniq, srcv, dstv, hT, hN, out);
}

// Round 23
// 99.102 us; speedup vs baseline: 1.0997x; 1.0997x over previous
//
#include <hip/hip_runtime.h>

#define NN 1024
#define DG 8
#define FO 64
#define FI 128
#define LALPHA 0.2f
#define BR 16        // rows per block (restored; R22's BR=8 doubled work, reverted)
#define SBS 257      // Sb row stride (u32 words)
#define RDS2 36      // aliased red row stride (floats, 32 cols + 4 pad)

typedef __attribute__((ext_vector_type(8))) short bf16x8;
typedef __attribute__((ext_vector_type(4))) float f32x4;

static __device__ __forceinline__ unsigned short f2bf(float x) {
  union { float f; unsigned u; } v; v.f = x;
  unsigned r = v.u + 0x7FFFu + ((v.u >> 16) & 1u);  // round-to-nearest-even
  return (unsigned short)(r >> 16);
}
static __device__ __forceinline__ float bf2f(unsigned short h) {
  union { unsigned u; float f; } v; v.u = ((unsigned)h) << 16;
  return v.f;
}

// ---------------------------------------------------------------------------
// K1 (prep): unchanged (measured 8.1 us, round 17).
// ---------------------------------------------------------------------------
__global__ __launch_bounds__(256) void k_prep(const float* __restrict__ atoms,
                                              const float* __restrict__ W,
                                              const float* __restrict__ a,
                                              const int* __restrict__ edges,
                                              int* __restrict__ uniq,
                                              ushort* __restrict__ hT,
                                              ushort* __restrict__ hN,
                                              float* __restrict__ srcv,
                                              float* __restrict__ dstv) {
  __shared__ float sp[16], dp[16];
  const int t = threadIdx.x, b = blockIdx.x;
  const int g = b >> 6;
  const int rbase = b * 16;

  if (t < 16) {
    sp[t] = 0.f; dp[t] = 0.f;
    const int rr = rbase + t;
    int e[DG];
#pragma unroll
    for (int s = 0; s < DG; s++) e[s] = edges[rr * DG + s];
#pragma unroll
    for (int s = 0; s < DG; s++) {
      int v = e[s];
      bool dup = false;
#pragma unroll
      for (int q = 0; q < DG; q++)
        if (q < s && e[q] == v) dup = true;
      uniq[rr * DG + s] = dup ? -1 : v;
    }
  }

  const int w = t >> 6, lane = t & 63, quad = lane >> 4, l16 = lane & 15;
  const float* __restrict__ Ar = atoms + (size_t)(rbase + l16) * FI;
  const float* __restrict__ Wc = W + w * 16 + l16;
  f32x4 acc = {0.f, 0.f, 0.f, 0.f};
#pragma unroll
  for (int kc = 0; kc < 4; kc++) {
    const int k0 = kc * 32 + quad * 8;
    float4 a0 = *(const float4*)(Ar + k0);
    float4 a1 = *(const float4*)(Ar + k0 + 4);
    float av[8] = {a0.x, a0.y, a0.z, a0.w, a1.x, a1.y, a1.z, a1.w};
    float wv[8];
#pragma unroll
    for (int e = 0; e < 8; e++) wv[e] = Wc[(k0 + e) * FO];
    bf16x8 ahi, alo, bhi, blo;
#pragma unroll
    for (int e = 0; e < 8; e++) {
      ushort h = f2bf(av[e]);
      ahi[e] = (short)h;
      alo[e] = (short)f2bf(av[e] - bf2f(h));
      ushort g2 = f2bf(wv[e]);
      bhi[e] = (short)g2;
      blo[e] = (short)f2bf(wv[e] - bf2f(g2));
    }
    acc = __builtin_amdgcn_mfma_f32_16x16x32_bf16(ahi, bhi, acc, 0, 0, 0);
    acc = __builtin_amdgcn_mfma_f32_16x16x32_bf16(ahi, blo, acc, 0, 0, 0);
    acc = __builtin_amdgcn_mfma_f32_16x16x32_bf16(alo, bhi, acc, 0, 0, 0);
  }

  const int f = w * 16 + l16;
  const float as_ = a[f], ad_ = a[FO + f];
  float ps[4], pd[4];
#pragma unroll
  for (int r = 0; r < 4; r++) {
    float v = acc[r];
    int rb = rbase + quad * 4 + r;
    ushort hv = f2bf(v);
    hT[((size_t)g * FO + f) * NN + (rb & (NN - 1))] = hv;
    hN[(size_t)rb * FO + f] = hv;
    ps[r] = v * as_;
    pd[r] = v * ad_;
  }
#pragma unroll
  for (int off = 1; off < 16; off <<= 1)
#pragma unroll
    for (int r = 0; r < 4; r++) {
      ps[r] += __shfl_xor(ps[r], off);
      pd[r] += __shfl_xor(pd[r], off);
    }
  __syncthreads();
  if (l16 == 0) {
#pragma unroll
    for (int r = 0; r < 4; r++) {
      atomicAdd(&sp[quad * 4 + r], ps[r]);
      atomicAdd(&dp[quad * 4 + r], pd[r]);
    }
  }
  __syncthreads();
  if (t < 16) {
    srcv[rbase + t] = sp[t];
    dstv[rbase + t] = dp[t];
  }
}

// ---------------------------------------------------------------------------
// K2 (fused): ROUND-23 -- F-SPLIT + Sb/red LDS ALIAS for 2x occupancy at
// CONSTANT total work (the R22 lesson: BR-halving duplicated GEMM; f-split
// does not). Block b: g=b>>7, rbase=((b&127)>>1)*16, fh=b&1 -> computes
// C[16 rows][32 cols] (ct tiles {2fh, 2fh+1}). Total MFMAs & hT traffic
// unchanged; scatter/softmax/exp-chain duplicate x2 (all <35% utilized).
// red[4][16][RDS2] ALIASES Sb (last Sb read is in GEMM; one extra barrier
// makes the overlay safe) -> LDS ~18 KB -> 8 blocks/CU = 32 waves/CU
// (was 16, Occupancy 40%, MfmaUtil 5.8%, VALUBusy 24% -- pure latency).
// Bit-identical per-element math (same gathers/k-order/reduction order).
// ---------------------------------------------------------------------------
__global__ __launch_bounds__(256, 8) void k_fused(const int* __restrict__ uniq,
                                                  const float* __restrict__ srcv,
                                                  const float* __restrict__ dstv,
                                                  const ushort* __restrict__ hT,
                                                  const ushort* __restrict__ hN,
                                                  float* __restrict__ out) {
  __shared__ __align__(16) unsigned SbU[BR * SBS];  // 16448 B; red aliases after GEMM
  __shared__ float zred[4][16];
  __shared__ int n1[BR][DG];
  __shared__ float attw[BR][DG];

  const int t = threadIdx.x, b = blockIdx.x;
  const int g = b >> 7, bl = b & 127;
  const int rbase = (bl >> 1) * BR, fh = bl & 1;
  const int* __restrict__ Ug = uniq + (size_t)g * NN * DG;
  float* __restrict__ redp = (float*)SbU;           // red[4][16][RDS2] = 9216 B

  for (int i = t; i < BR * SBS; i += 256) SbU[i] = 0u;
  if (t < BR * DG) n1[t >> 3][t & 7] = Ug[(rbase + (t >> 3)) * DG + (t & 7)];
  __syncthreads();

  // --- scatter: 1024 items (r = idx&15, e = idx>>4), levels 1..3 fused ---
#pragma unroll
  for (int q = 0; q < 4; q++) {
    int idx = t + 256 * q;
    int r = idx & 15, e = idx >> 4;
    int j = n1[r][e >> 3];
    if (j >= 0) {
      if ((e & 7) == 0)  // level-1, once per (r,s)
        atomicAdd(&SbU[r * SBS + (j >> 2)], 1u << ((j & 3) * 8));
      int k = Ug[j * DG + (e & 7)];
      if (k >= 0) {
        atomicAdd(&SbU[r * SBS + (k >> 2)], 1u << ((k & 3) * 8));  // level-2
        int4 m0 = *(const int4*)(Ug + k * DG);
        int4 m1 = *(const int4*)(Ug + k * DG + 4);
        int ll[8] = {m0.x, m0.y, m0.z, m0.w, m1.x, m1.y, m1.z, m1.w};
#pragma unroll
        for (int e2 = 0; e2 < 8; e2++)  // level-3
          if (ll[e2] >= 0) atomicAdd(&SbU[r * SBS + (ll[e2] >> 2)], 1u << ((ll[e2] & 3) * 8));
      }
    }
  }
  // att softmax (t<16, one row each)
  if (t < BR) {
    int r = t;
    float si = srcv[g * NN + rbase + r];
    float ev[DG];
    float m = -1e30f;
#pragma unroll
    for (int s = 0; s < DG; s++) {
      int j = n1[r][s];
      if (j >= 0) {
        float x = si + dstv[g * NN + j];
        x = x > 0.f ? x : LALPHA * x;
        ev[s] = x;
        m = fmaxf(m, x);
      } else ev[s] = -1e30f;
    }
    float sm = 0.f;
#pragma unroll
    for (int s = 0; s < DG; s++) {
      float e = (n1[r][s] >= 0) ? __expf(ev[s] - m) : 0.f;
      ev[s] = e;
      sm += e;
    }
    float inv = 1.f / sm;
#pragma unroll
    for (int s = 0; s < DG; s++) attw[r][s] = ev[s] * inv;
  }
  __syncthreads();

  // --- attH in REGISTERS: t<128 -> (row rr_=t>>3, cols fh*32+(t&7)*4) ---
  const int rr_ = t >> 3, f0l = (t & 7) * 4;
  const int fgl = fh * 32 + f0l;
  float ah0 = 0.f, ah1 = 0.f, ah2 = 0.f, ah3 = 0.f;
  if (t < BR * 8) {
#pragma unroll
    for (int s = 0; s < DG; s++) {
      int j = n1[rr_][s];
      if (j >= 0) {
        float wgt = attw[rr_][s];
        uint2 hv = *(const uint2*)(hN + ((size_t)(g * NN + j)) * FO + fgl);
        ah0 += wgt * bf2f((ushort)(hv.x & 0xffffu));
        ah1 += wgt * bf2f((ushort)(hv.x >> 16));
        ah2 += wgt * bf2f((ushort)(hv.y & 0xffffu));
        ah3 += wgt * bf2f((ushort)(hv.y >> 16));
      }
    }
  }

  // --- k-split GEMM: wave v covers k [v*256, +256); 2 ct-tiles (fh half) ---
  const int v = t >> 6, lane = t & 63, quad = lane >> 4, l16 = lane & 15;
  const int k0 = v * 256;
  const ushort* __restrict__ hb = hT + ((size_t)g * FO) * NN;
  const size_t cof = (size_t)(fh * 32) * NN;
  f32x4 acc0 = {0.f, 0.f, 0.f, 0.f}, acc1 = {0.f, 0.f, 0.f, 0.f};
  float zacc = 0.f;
#pragma unroll
  for (int ks = 0; ks < 256; ks += 32) {
    const int wd = l16 * SBS + ((k0 + ks) >> 2) + quad * 2;
    unsigned s0 = SbU[wd], s1 = SbU[wd + 1];
    const int c0 = s0 & 255u, c1 = (s0 >> 8) & 255u, c2 = (s0 >> 16) & 255u, c3 = s0 >> 24;
    const int c4 = s1 & 255u, c5 = (s1 >> 8) & 255u, c6 = (s1 >> 16) & 255u, c7 = s1 >> 24;
    const float e0 = __expf((float)c0), e1 = __expf((float)c1);
    const float e2 = __expf((float)c2), e3 = __expf((float)c3);
    const float e4 = __expf((float)c4), e5 = __expf((float)c5);
    const float e6 = __expf((float)c6), e7 = __expf((float)c7);
    bf16x8 af;
    af[0] = (short)f2bf(e0); af[1] = (short)f2bf(e1);
    af[2] = (short)f2bf(e2); af[3] = (short)f2bf(e3);
    af[4] = (short)f2bf(e4); af[5] = (short)f2bf(e5);
    af[6] = (short)f2bf(e6); af[7] = (short)f2bf(e7);
    zacc += (e0 + e1) + (e2 + e3) + (e4 + e5) + (e6 + e7);
    const ushort* hp = hb + (size_t)l16 * NN + k0 + ks + quad * 8;
    bf16x8 bA = *(const bf16x8*)(hp + cof);
    bf16x8 bB = *(const bf16x8*)(hp + cof + (size_t)16 * NN);
    acc0 = __builtin_amdgcn_mfma_f32_16x16x32_bf16(af, bA, acc0, 0, 0, 0);
    acc1 = __builtin_amdgcn_mfma_f32_16x16x32_bf16(af, bB, acc1, 0, 0, 0);
  }
  zacc += __shfl_xor(zacc, 16);
  zacc += __shfl_xor(zacc, 32);

  __syncthreads();  // ALL waves done reading SbU -> safe to overlay red

  if (lane < 16) zred[v][lane] = zacc;
#pragma unroll
  for (int r = 0; r < 4; r++) {
    redp[((v * 16) + quad * 4 + r) * RDS2 + 0 * 16 + l16] = acc0[r];
    redp[((v * 16) + quad * 4 + r) * RDS2 + 1 * 16 + l16] = acc1[r];
  }
  __syncthreads();

  // --- epilogue: t<128 -> (row rr_, local cols f0l..+3), coalesced float4 ---
  if (t < BR * 8) {
    const float Z = zred[0][rr_] + zred[1][rr_] + zred[2][rr_] + zred[3][rr_];
    const float hz = 0.5f / Z;
    f32x4 s = *(const f32x4*)&redp[(0 * 16 + rr_) * RDS2 + f0l];
    f32x4 s1v = *(const f32x4*)&redp[(1 * 16 + rr_) * RDS2 + f0l];
    f32x4 s2v = *(const f32x4*)&redp[(2 * 16 + rr_) * RDS2 + f0l];
    f32x4 s3v = *(const f32x4*)&redp[(3 * 16 + rr_) * RDS2 + f0l];
    float o0 = 0.5f * ah0 + (s[0] + s1v[0] + s2v[0] + s3v[0]) * hz;
    float o1 = 0.5f * ah1 + (s[1] + s1v[1] + s2v[1] + s3v[1]) * hz;
    float o2 = 0.5f * ah2 + (s[2] + s1v[2] + s2v[2] + s3v[2]) * hz;
    float o3 = 0.5f * ah3 + (s[3] + s1v[3] + s2v[3] + s3v[3]) * hz;
    o0 = o0 > 0.f ? o0 : __expf(o0) - 1.f;
    o1 = o1 > 0.f ? o1 : __expf(o1) - 1.f;
    o2 = o2 > 0.f ? o2 : __expf(o2) - 1.f;
    o3 = o3 > 0.f ? o3 : __expf(o3) - 1.f;
    *(float4*)(out + ((size_t)(g * NN + rbase + rr_)) * FO + fgl) =
        make_float4(o0, o1, o2, o3);
  }
}

// ---------------------------------------------------------------------------
extern "C" void kernel_launch(void* const* d_in, const int* in_sizes, int n_in,
                              void* d_out, int out_size, void* d_ws, size_t ws_size,
                              hipStream_t stream) {
  const float* atoms = (const float*)d_in[0];
  const int* edges = (const int*)d_in[1];
  const float* W = (const float*)d_in[2];
  const float* a = (const float*)d_in[3];
  float* out = (float*)d_out;

  const int nrows = in_sizes[0] / FI;   // B*N = 16384
  const int ngraph = nrows / NN;        // 16

  ushort* hT = (ushort*)d_ws;                                   // ngraph*FO*NN
  ushort* hN = hT + (size_t)ngraph * FO * NN;                   // nrows*FO
  float* srcv = (float*)(hN + (size_t)nrows * FO);              // nrows
  float* dstv = srcv + nrows;                                   // nrows
  int* uniq = (int*)(dstv + nrows);                             // nrows*DG

  k_prep<<<nrows / 16, 256, 0, stream>>>(atoms, W, a, edges, uniq, hT, hN, srcv, dstv);
  k_fused<<<ngraph * 128, 256, 0, stream>>>(uniq, srcv, dstv, hT, hN, out);
}

// Round 25
// 97.646 us; speedup vs baseline: 1.1161x; 1.0149x over previous
//
#include <hip/hip_runtime.h>

#define NN 1024
#define DG 8
#define FO 64
#define FI 128
#define LALPHA 0.2f
#define BR 32        // rows per block (R24: 16 -> 32, halves hT L2-line traffic)
#define SBS 257      // Sb row stride (u32 words)
#define RDS 68       // red row stride (floats)

typedef __attribute__((ext_vector_type(8))) short bf16x8;
typedef __attribute__((ext_vector_type(4))) float f32x4;

static __device__ __forceinline__ unsigned short f2bf(float x) {
  union { float f; unsigned u; } v; v.f = x;
  unsigned r = v.u + 0x7FFFu + ((v.u >> 16) & 1u);  // round-to-nearest-even
  return (unsigned short)(r >> 16);
}
static __device__ __forceinline__ float bf2f(unsigned short h) {
  union { unsigned u; float f; } v; v.u = ((unsigned)h) << 16;
  return v.f;
}

// ---------------------------------------------------------------------------
// K1 (prep): unchanged (measured 8.1 us, round 17).
// ---------------------------------------------------------------------------
__global__ __launch_bounds__(256) void k_prep(const float* __restrict__ atoms,
                                              const float* __restrict__ W,
                                              const float* __restrict__ a,
                                              const int* __restrict__ edges,
                                              int* __restrict__ uniq,
                                              ushort* __restrict__ hT,
                                              ushort* __restrict__ hN,
                                              float* __restrict__ srcv,
                                              float* __restrict__ dstv) {
  __shared__ float sp[16], dp[16];
  const int t = threadIdx.x, b = blockIdx.x;
  const int g = b >> 6;
  const int rbase = b * 16;

  if (t < 16) {
    sp[t] = 0.f; dp[t] = 0.f;
    const int rr = rbase + t;
    int e[DG];
#pragma unroll
    for (int s = 0; s < DG; s++) e[s] = edges[rr * DG + s];
#pragma unroll
    for (int s = 0; s < DG; s++) {
      int v = e[s];
      bool dup = false;
#pragma unroll
      for (int q = 0; q < DG; q++)
        if (q < s && e[q] == v) dup = true;
      uniq[rr * DG + s] = dup ? -1 : v;
    }
  }

  const int w = t >> 6, lane = t & 63, quad = lane >> 4, l16 = lane & 15;
  const float* __restrict__ Ar = atoms + (size_t)(rbase + l16) * FI;
  const float* __restrict__ Wc = W + w * 16 + l16;
  f32x4 acc = {0.f, 0.f, 0.f, 0.f};
#pragma unroll
  for (int kc = 0; kc < 4; kc++) {
    const int k0 = kc * 32 + quad * 8;
    float4 a0 = *(const float4*)(Ar + k0);
    float4 a1 = *(const float4*)(Ar + k0 + 4);
    float av[8] = {a0.x, a0.y, a0.z, a0.w, a1.x, a1.y, a1.z, a1.w};
    float wv[8];
#pragma unroll
    for (int e = 0; e < 8; e++) wv[e] = Wc[(k0 + e) * FO];
    bf16x8 ahi, alo, bhi, blo;
#pragma unroll
    for (int e = 0; e < 8; e++) {
      ushort h = f2bf(av[e]);
      ahi[e] = (short)h;
      alo[e] = (short)f2bf(av[e] - bf2f(h));
      ushort g2 = f2bf(wv[e]);
      bhi[e] = (short)g2;
      blo[e] = (short)f2bf(wv[e] - bf2f(g2));
    }
    acc = __builtin_amdgcn_mfma_f32_16x16x32_bf16(ahi, bhi, acc, 0, 0, 0);
    acc = __builtin_amdgcn_mfma_f32_16x16x32_bf16(ahi, blo, acc, 0, 0, 0);
    acc = __builtin_amdgcn_mfma_f32_16x16x32_bf16(alo, bhi, acc, 0, 0, 0);
  }

  const int f = w * 16 + l16;
  const float as_ = a[f], ad_ = a[FO + f];
  float ps[4], pd[4];
#pragma unroll
  for (int r = 0; r < 4; r++) {
    float v = acc[r];
    int rb = rbase + quad * 4 + r;
    ushort hv = f2bf(v);
    hT[((size_t)g * FO + f) * NN + (rb & (NN - 1))] = hv;
    hN[(size_t)rb * FO + f] = hv;
    ps[r] = v * as_;
    pd[r] = v * ad_;
  }
#pragma unroll
  for (int off = 1; off < 16; off <<= 1)
#pragma unroll
    for (int r = 0; r < 4; r++) {
      ps[r] += __shfl_xor(ps[r], off);
      pd[r] += __shfl_xor(pd[r], off);
    }
  __syncthreads();
  if (l16 == 0) {
#pragma unroll
    for (int r = 0; r < 4; r++) {
      atomicAdd(&sp[quad * 4 + r], ps[r]);
      atomicAdd(&dp[quad * 4 + r], pd[r]);
    }
  }
  __syncthreads();
  if (t < 16) {
    srcv[rbase + t] = sp[t];
    dstv[rbase + t] = dp[t];
  }
}

// ---------------------------------------------------------------------------
// K2 (fused): ROUND-24 -- BR=32. The L2-LINE-THROUGHPUT model (fits R20's
// 15.3us GEMM: 8K lines/CU x ~4cyc = 32K cyc; postdicts R22's +12.3 and
// R23's +2.4) says the lever is hT bytes/CU. With 32 rows/block the two
// 16-row MFMA tiles SHARE the B-operand loads -> total hT line traffic
// HALVES (512 blocks x same lines/block). Sb[32][257] aliased under
// red[4][32][68] (union, barrier-separated) -> ~37KB LDS, 2 blocks/CU,
// 8 waves/CU (enough if transaction-bound -- this is the model's test).
// Per-element arithmetic identical -> absmax unchanged.
// ---------------------------------------------------------------------------
__global__ __launch_bounds__(256, 2) void k_fused(const int* __restrict__ uniq,
                                                  const float* __restrict__ srcv,
                                                  const float* __restrict__ dstv,
                                                  const ushort* __restrict__ hT,
                                                  const ushort* __restrict__ hN,
                                                  float* __restrict__ out) {
  __shared__ __align__(16) float redU[4 * BR * RDS];  // 34816 B; Sb aliases front
  __shared__ float zred[4][BR];
  __shared__ int n1[BR][DG];
  __shared__ float attw[BR][DG];
  unsigned* __restrict__ Sb = (unsigned*)redU;        // 32*257 = 8224 words

  const int t = threadIdx.x, b = blockIdx.x;
  const int g = b >> 5, rbase = (b & 31) * BR;
  const int* __restrict__ Ug = uniq + (size_t)g * NN * DG;

  for (int i = t; i < BR * SBS; i += 256) Sb[i] = 0u;
  n1[t >> 3][t & 7] = Ug[(rbase + (t >> 3)) * DG + (t & 7)];  // 256 = 32*8
  __syncthreads();

  // --- scatter: 2048 items (r = idx&31, e = idx>>5), levels 1..3 fused ---
#pragma unroll
  for (int q = 0; q < 8; q++) {
    int idx = t + 256 * q;
    int r = idx & 31, e = idx >> 5;
    int j = n1[r][e >> 3];
    if (j >= 0) {
      if ((e & 7) == 0)  // level-1, once per (r,s)
        atomicAdd(&Sb[r * SBS + (j >> 2)], 1u << ((j & 3) * 8));
      int k = Ug[j * DG + (e & 7)];
      if (k >= 0) {
        atomicAdd(&Sb[r * SBS + (k >> 2)], 1u << ((k & 3) * 8));  // level-2
        int4 m0 = *(const int4*)(Ug + k * DG);
        int4 m1 = *(const int4*)(Ug + k * DG + 4);
        int ll[8] = {m0.x, m0.y, m0.z, m0.w, m1.x, m1.y, m1.z, m1.w};
#pragma unroll
        for (int e2 = 0; e2 < 8; e2++)  // level-3
          if (ll[e2] >= 0) atomicAdd(&Sb[r * SBS + (ll[e2] >> 2)], 1u << ((ll[e2] & 3) * 8));
      }
    }
  }
  // att softmax (t<32, one row each)
  if (t < BR) {
    int r = t;
    float si = srcv[g * NN + rbase + r];
    float ev[DG];
    float m = -1e30f;
#pragma unroll
    for (int s = 0; s < DG; s++) {
      int j = n1[r][s];
      if (j >= 0) {
        float x = si + dstv[g * NN + j];
        x = x > 0.f ? x : LALPHA * x;
        ev[s] = x;
        m = fmaxf(m, x);
      } else ev[s] = -1e30f;
    }
    float sm = 0.f;
#pragma unroll
    for (int s = 0; s < DG; s++) {
      float e = (n1[r][s] >= 0) ? __expf(ev[s] - m) : 0.f;
      ev[s] = e;
      sm += e;
    }
    float inv = 1.f / sm;
#pragma unroll
    for (int s = 0; s < DG; s++) attw[r][s] = ev[s] * inv;
  }
  __syncthreads();

  // --- attH in REGISTERS: thread t -> rows rA=t>>4 and rA+16, cols f0_ ---
  const int rA = t >> 4, rB = rA + 16, f0_ = (t & 15) * 4;
  float aA0 = 0.f, aA1 = 0.f, aA2 = 0.f, aA3 = 0.f;
  float aB0 = 0.f, aB1 = 0.f, aB2 = 0.f, aB3 = 0.f;
#pragma unroll
  for (int s = 0; s < DG; s++) {
    int j = n1[rA][s];
    if (j >= 0) {
      float wgt = attw[rA][s];
      uint2 hv = *(const uint2*)(hN + ((size_t)(g * NN + j)) * FO + f0_);
      aA0 += wgt * bf2f((ushort)(hv.x & 0xffffu));
      aA1 += wgt * bf2f((ushort)(hv.x >> 16));
      aA2 += wgt * bf2f((ushort)(hv.y & 0xffffu));
      aA3 += wgt * bf2f((ushort)(hv.y >> 16));
    }
  }
#pragma unroll
  for (int s = 0; s < DG; s++) {
    int j = n1[rB][s];
    if (j >= 0) {
      float wgt = attw[rB][s];
      uint2 hv = *(const uint2*)(hN + ((size_t)(g * NN + j)) * FO + f0_);
      aB0 += wgt * bf2f((ushort)(hv.x & 0xffffu));
      aB1 += wgt * bf2f((ushort)(hv.x >> 16));
      aB2 += wgt * bf2f((ushort)(hv.y & 0xffffu));
      aB3 += wgt * bf2f((ushort)(hv.y >> 16));
    }
  }

  // --- k-split GEMM: wave v covers k [v*256,+256); TWO 16-row A tiles share
  //     the SAME B loads (the line-traffic halving) ---
  const int v = t >> 6, lane = t & 63, quad = lane >> 4, l16 = lane & 15;
  const int k0 = v * 256;
  const ushort* __restrict__ hb = hT + ((size_t)g * FO) * NN;
  f32x4 accA[4] = {{0.f, 0.f, 0.f, 0.f}, {0.f, 0.f, 0.f, 0.f},
                   {0.f, 0.f, 0.f, 0.f}, {0.f, 0.f, 0.f, 0.f}};
  f32x4 accB[4] = {{0.f, 0.f, 0.f, 0.f}, {0.f, 0.f, 0.f, 0.f},
                   {0.f, 0.f, 0.f, 0.f}, {0.f, 0.f, 0.f, 0.f}};
  float zaccA = 0.f, zaccB = 0.f;
#pragma unroll
  for (int ks = 0; ks < 256; ks += 32) {
    const int wof = ((k0 + ks) >> 2) + quad * 2;
    unsigned sA0 = Sb[l16 * SBS + wof], sA1 = Sb[l16 * SBS + wof + 1];
    unsigned sB0 = Sb[(l16 + 16) * SBS + wof], sB1 = Sb[(l16 + 16) * SBS + wof + 1];
    // row-tile A exp chain
    {
      const int c0 = sA0 & 255u, c1 = (sA0 >> 8) & 255u, c2 = (sA0 >> 16) & 255u, c3 = sA0 >> 24;
      const int c4 = sA1 & 255u, c5 = (sA1 >> 8) & 255u, c6 = (sA1 >> 16) & 255u, c7 = sA1 >> 24;
      const float e0 = __expf((float)c0), e1 = __expf((float)c1);
      const float e2 = __expf((float)c2), e3 = __expf((float)c3);
      const float e4 = __expf((float)c4), e5 = __expf((float)c5);
      const float e6 = __expf((float)c6), e7 = __expf((float)c7);
      bf16x8 afA;
      afA[0] = (short)f2bf(e0); afA[1] = (short)f2bf(e1);
      afA[2] = (short)f2bf(e2); afA[3] = (short)f2bf(e3);
      afA[4] = (short)f2bf(e4); afA[5] = (short)f2bf(e5);
      afA[6] = (short)f2bf(e6); afA[7] = (short)f2bf(e7);
      zaccA += (e0 + e1) + (e2 + e3) + (e4 + e5) + (e6 + e7);
      const int c8 = sB0 & 255u, c9 = (sB0 >> 8) & 255u, ca = (sB0 >> 16) & 255u, cb = sB0 >> 24;
      const int cc = sB1 & 255u, cd = (sB1 >> 8) & 255u, ce = (sB1 >> 16) & 255u, cf = sB1 >> 24;
      const float f0 = __expf((float)c8), f1 = __expf((float)c9);
      const float f2 = __expf((float)ca), f3 = __expf((float)cb);
      const float f4 = __expf((float)cc), f5 = __expf((float)cd);
      const float f6 = __expf((float)ce), f7 = __expf((float)cf);
      bf16x8 afB;
      afB[0] = (short)f2bf(f0); afB[1] = (short)f2bf(f1);
      afB[2] = (short)f2bf(f2); afB[3] = (short)f2bf(f3);
      afB[4] = (short)f2bf(f4); afB[5] = (short)f2bf(f5);
      afB[6] = (short)f2bf(f6); afB[7] = (short)f2bf(f7);
      zaccB += (f0 + f1) + (f2 + f3) + (f4 + f5) + (f6 + f7);
      const ushort* hp = hb + (size_t)l16 * NN + k0 + ks + quad * 8;
#pragma unroll
      for (int ct = 0; ct < 4; ct++) {
        bf16x8 bf = *(const bf16x8*)(hp + (size_t)(ct * 16) * NN);  // shared B
        accA[ct] = __builtin_amdgcn_mfma_f32_16x16x32_bf16(afA, bf, accA[ct], 0, 0, 0);
        accB[ct] = __builtin_amdgcn_mfma_f32_16x16x32_bf16(afB, bf, accB[ct], 0, 0, 0);
      }
    }
  }
  zaccA += __shfl_xor(zaccA, 16);
  zaccA += __shfl_xor(zaccA, 32);
  zaccB += __shfl_xor(zaccB, 16);
  zaccB += __shfl_xor(zaccB, 32);

  __syncthreads();  // ALL waves done reading Sb -> safe to overlay red

  if (lane < 16) {
    zred[v][l16] = zaccA;
    zred[v][l16 + 16] = zaccB;
  }
#pragma unroll
  for (int ct = 0; ct < 4; ct++)
#pragma unroll
    for (int r = 0; r < 4; r++) {
      redU[((size_t)v * BR + quad * 4 + r) * RDS + ct * 16 + l16] = accA[ct][r];
      redU[((size_t)v * BR + 16 + quad * 4 + r) * RDS + ct * 16 + l16] = accB[ct][r];
    }
  __syncthreads();

  // --- epilogue: thread t -> rows rA, rB at cols f0_..f0_+4, float4 x2 ---
  {
    const float ZA = zred[0][rA] + zred[1][rA] + zred[2][rA] + zred[3][rA];
    const float hzA = 0.5f / ZA;
    f32x4 s = *(const f32x4*)&redU[((size_t)0 * BR + rA) * RDS + f0_];
    f32x4 s1v = *(const f32x4*)&redU[((size_t)1 * BR + rA) * RDS + f0_];
    f32x4 s2v = *(const f32x4*)&redU[((size_t)2 * BR + rA) * RDS + f0_];
    f32x4 s3v = *(const f32x4*)&redU[((size_t)3 * BR + rA) * RDS + f0_];
    float o0 = 0.5f * aA0 + (s[0] + s1v[0] + s2v[0] + s3v[0]) * hzA;
    float o1 = 0.5f * aA1 + (s[1] + s1v[1] + s2v[1] + s3v[1]) * hzA;
    float o2 = 0.5f * aA2 + (s[2] + s1v[2] + s2v[2] + s3v[2]) * hzA;
    float o3 = 0.5f * aA3 + (s[3] + s1v[3] + s2v[3] + s3v[3]) * hzA;
    o0 = o0 > 0.f ? o0 : __expf(o0) - 1.f;
    o1 = o1 > 0.f ? o1 : __expf(o1) - 1.f;
    o2 = o2 > 0.f ? o2 : __expf(o2) - 1.f;
    o3 = o3 > 0.f ? o3 : __expf(o3) - 1.f;
    *(float4*)(out + ((size_t)(g * NN + rbase + rA)) * FO + f0_) =
        make_float4(o0, o1, o2, o3);
  }
  {
    const float ZB = zred[0][rB] + zred[1][rB] + zred[2][rB] + zred[3][rB];
    const float hzB = 0.5f / ZB;
    f32x4 s = *(const f32x4*)&redU[((size_t)0 * BR + rB) * RDS + f0_];
    f32x4 s1v = *(const f32x4*)&redU[((size_t)1 * BR + rB) * RDS + f0_];
    f32x4 s2v = *(const f32x4*)&redU[((size_t)2 * BR + rB) * RDS + f0_];
    f32x4 s3v = *(const f32x4*)&redU[((size_t)3 * BR + rB) * RDS + f0_];
    float o0 = 0.5f * aB0 + (s[0] + s1v[0] + s2v[0] + s3v[0]) * hzB;
    float o1 = 0.5f * aB1 + (s[1] + s1v[1] + s2v[1] + s3v[1]) * hzB;
    float o2 = 0.5f * aB2 + (s[2] + s1v[2] + s2v[2] + s3v[2]) * hzB;
    float o3 = 0.5f * aB3 + (s[3] + s1v[3] + s2v[3] + s3v[3]) * hzB;
    o0 = o0 > 0.f ? o0 : __expf(o0) - 1.f;
    o1 = o1 > 0.f ? o1 : __expf(o1) - 1.f;
    o2 = o2 > 0.f ? o2 : __expf(o2) - 1.f;
    o3 = o3 > 0.f ? o3 : __expf(o3) - 1.f;
    *(float4*)(out + ((size_t)(g * NN + rbase + rB)) * FO + f0_) =
        make_float4(o0, o1, o2, o3);
  }
}

// ---------------------------------------------------------------------------
extern "C" void kernel_launch(void* const* d_in, const int* in_sizes, int n_in,
                              void* d_out, int out_size, void* d_ws, size_t ws_size,
                              hipStream_t stream) {
  const float* atoms = (const float*)d_in[0];
  const int* edges = (const int*)d_in[1];
  const float* W = (const float*)d_in[2];
  const float* a = (const float*)d_in[3];
  float* out = (float*)d_out;

  const int nrows = in_sizes[0] / FI;   // B*N = 16384
  const int ngraph = nrows / NN;        // 16

  ushort* hT = (ushort*)d_ws;                                   // ngraph*FO*NN
  ushort* hN = hT + (size_t)ngraph * FO * NN;                   // nrows*FO
  float* srcv = (float*)(hN + (size_t)nrows * FO);              // nrows
  float* dstv = srcv + nrows;                                   // nrows
  int* uniq = (int*)(dstv + nrows);                             // nrows*DG

  k_prep<<<nrows / 16, 256, 0, stream>>>(atoms, W, a, edges, uniq, hT, hN, srcv, dstv);
  k_fused<<<ngraph * (NN / BR), 256, 0, stream>>>(uniq, srcv, dstv, hT, hN, out);
}